// Round 3
// baseline (406.820 us; speedup 1.0000x reference)
//
#include <hip/hip_runtime.h>
#include <math.h>

// Quantum circuit collapses analytically:
//   z_w = cos(q_params[w]) * cos(features[w])   (RZ layer is pure phase -> no-op on probs)
//   q_out = [z0, z0*z1, z0*z1*z2, z0*z1*z2*z3]  (CNOT chain = parity of independent bits)
// Then MLP 4->64 (relu) -> 4, batchnorm over batch.
//
// k_main: 256-thread block handles 64 images. 16 lanes cooperatively load one
// image (coalesced within the image's ~832B footprint), shfl_xor(width=16)
// reduce pooled features, LDS hand-off, then 64 threads do the MLPs at full
// lane utilization. 1024 blocks -> 4 blocks/CU (vs 1 before).

__global__ void k_init(float* acc) {
    if (threadIdx.x < 8) acc[threadIdx.x] = 0.0f;
}

#define IMGS_PER_BLOCK 64

__global__ __launch_bounds__(256) void k_main(
    const float* __restrict__ x,
    const float* __restrict__ qp,
    const float* __restrict__ W1,
    const float* __restrict__ b1,
    const float* __restrict__ W2,
    const float* __restrict__ b2,
    float* __restrict__ logits,
    float* __restrict__ acc,
    int B)
{
    __shared__ float sW1[256];   // [j][w], row-major 64x4
    __shared__ float sW2t[256];  // [j][k]  (transpose of W2 4x64)
    __shared__ float sb1[64];
    __shared__ float sfeat[IMGS_PER_BLOCK][4];
    __shared__ float sred[32];   // 4 waves x 8 partials

    const int tid = threadIdx.x;
    sW1[tid]  = W1[tid];
    sW2t[tid] = W2[(tid & 3) * 64 + (tid >> 2)];
    if (tid < 64) sb1[tid] = b1[tid];

    // ---- Phase 1: cooperative pooled-feature load ----
    // group g = tid>>4 (16 groups), lane l = tid&15. Round r: group g loads
    // image (blockIdx*64 + r*16 + g). Image needs float4 indices 0..35:
    // lane l takes idx {l, l+16, l+32(if l<4)}. idx -> row=idx/6, col=idx%6.
    const int g = tid >> 4, l = tid & 15;
    const int img_base = blockIdx.x * IMGS_PER_BLOCK;

    #pragma unroll
    for (int r = 0; r < 4; ++r) {
        const int li  = r * 16 + g;          // local image index 0..63
        const int img = img_base + li;
        float f0 = 0.f, f1 = 0.f, f2 = 0.f, f3 = 0.f;
        if (img < B) {
            const float* xb = x + (size_t)img * 1296;
            #pragma unroll
            for (int k = 0; k < 3; ++k) {
                const int idx = l + k * 16;
                if (k == 2 && l >= 4) break;          // idx 32..35 only
                const int row = (idx * 43) >> 8;      // idx/6 for idx<36
                const int col = idx - 6 * row;
                float4 v = ((const float4*)(xb + row * 36))[col];
                float lo = v.x + v.y, hi = v.z + v.w, tot = lo + hi;
                f0 += (col == 0) ? tot : (col == 1) ? lo : 0.f;
                f1 += (col == 2) ? tot : (col == 1) ? hi : 0.f;
                f2 += (col == 3) ? tot : (col == 4) ? lo : 0.f;
                f3 += (col == 5) ? tot : (col == 4) ? hi : 0.f;
            }
        }
        #pragma unroll
        for (int m = 1; m < 16; m <<= 1) {
            f0 += __shfl_xor(f0, m, 16);
            f1 += __shfl_xor(f1, m, 16);
            f2 += __shfl_xor(f2, m, 16);
            f3 += __shfl_xor(f3, m, 16);
        }
        if (l == 0) {
            sfeat[li][0] = f0; sfeat[li][1] = f1;
            sfeat[li][2] = f2; sfeat[li][3] = f3;
        }
    }
    __syncthreads();

    // ---- Phase 2: per-image circuit + MLP (threads 0..63) ----
    float l0 = 0.f, l1 = 0.f, l2 = 0.f, l3 = 0.f;
    const int img = img_base + tid;
    if (tid < IMGS_PER_BLOCK && img < B) {
        const float inv36 = 1.0f / 36.0f;
        float z0 = cosf(qp[0]) * cosf(sfeat[tid][0] * inv36);
        float z1 = cosf(qp[1]) * cosf(sfeat[tid][1] * inv36);
        float z2 = cosf(qp[2]) * cosf(sfeat[tid][2] * inv36);
        float z3 = cosf(qp[3]) * cosf(sfeat[tid][3] * inv36);
        float q0 = z0;
        float q1 = q0 * z1;
        float q2 = q1 * z2;
        float q3 = q2 * z3;

        l0 = b2[0]; l1 = b2[1]; l2 = b2[2]; l3 = b2[3];
        #pragma unroll 8
        for (int j = 0; j < 64; ++j) {
            float h = sb1[j];
            h = fmaf(sW1[4*j+0], q0, h);
            h = fmaf(sW1[4*j+1], q1, h);
            h = fmaf(sW1[4*j+2], q2, h);
            h = fmaxf(fmaf(sW1[4*j+3], q3, h), 0.0f);
            l0 = fmaf(sW2t[4*j+0], h, l0);
            l1 = fmaf(sW2t[4*j+1], h, l1);
            l2 = fmaf(sW2t[4*j+2], h, l2);
            l3 = fmaf(sW2t[4*j+3], h, l3);
        }
        ((float4*)logits)[img] = make_float4(l0, l1, l2, l3);
    }

    // ---- batchnorm partials (inactive threads contribute 0) ----
    float v[8] = {l0, l1, l2, l3, l0*l0, l1*l1, l2*l2, l3*l3};
    #pragma unroll
    for (int off = 32; off >= 1; off >>= 1) {
        #pragma unroll
        for (int i = 0; i < 8; ++i) v[i] += __shfl_down(v[i], off);
    }
    const int lane = tid & 63, wv = tid >> 6;
    if (lane == 0) {
        #pragma unroll
        for (int i = 0; i < 8; ++i) sred[wv * 8 + i] = v[i];
    }
    __syncthreads();
    if (tid < 8) {
        float s = sred[tid] + sred[tid + 8] + sred[tid + 16] + sred[tid + 24];
        atomicAdd(&acc[tid], s);
    }
}

__global__ __launch_bounds__(256) void k_norm(
    const float* __restrict__ logits,
    const float* __restrict__ acc,
    const float* __restrict__ gamma,
    const float* __restrict__ beta,
    float* __restrict__ out,
    int B, float invB)
{
    __shared__ float sc[4], sh[4];
    if (threadIdx.x < 4) {
        const int k = threadIdx.x;
        float mu   = acc[k] * invB;
        float var  = acc[4 + k] * invB - mu * mu;
        float rstd = 1.0f / sqrtf(var + 1e-5f);
        float g = gamma[k] * rstd;
        sc[k] = g;
        sh[k] = beta[k] - mu * g;
    }
    __syncthreads();
    const int b = blockIdx.x * 256 + threadIdx.x;
    if (b >= B) return;
    float4 l = ((const float4*)logits)[b];
    float4 o;
    o.x = fmaf(sc[0], l.x, sh[0]);
    o.y = fmaf(sc[1], l.y, sh[1]);
    o.z = fmaf(sc[2], l.z, sh[2]);
    o.w = fmaf(sc[3], l.w, sh[3]);
    ((float4*)out)[b] = o;
}

extern "C" void kernel_launch(void* const* d_in, const int* in_sizes, int n_in,
                              void* d_out, int out_size, void* d_ws, size_t ws_size,
                              hipStream_t stream) {
    const float* x     = (const float*)d_in[0];
    const float* qp    = (const float*)d_in[1];
    const float* W1    = (const float*)d_in[2];
    const float* b1    = (const float*)d_in[3];
    const float* W2    = (const float*)d_in[4];
    const float* b2    = (const float*)d_in[5];
    const float* gamma = (const float*)d_in[6];
    const float* beta  = (const float*)d_in[7];
    float* out = (float*)d_out;

    const int B = in_sizes[0] / 1296;           // 65536
    float* acc    = (float*)d_ws;               // 8 floats: sum[4], sumsq[4]
    float* logits = (float*)d_ws + 64;          // B*4 floats, 256B offset keeps float4 alignment

    const int nb_main = (B + IMGS_PER_BLOCK - 1) / IMGS_PER_BLOCK;
    const int nb_norm = (B + 255) / 256;
    hipLaunchKernelGGL(k_init, dim3(1), dim3(64), 0, stream, acc);
    hipLaunchKernelGGL(k_main, dim3(nb_main), dim3(256), 0, stream,
                       x, qp, W1, b1, W2, b2, logits, acc, B);
    hipLaunchKernelGGL(k_norm, dim3(nb_norm), dim3(256), 0, stream,
                       logits, acc, gamma, beta, out, B, 1.0f / (float)B);
}